// Round 14
// baseline (233.575 us; speedup 1.0000x reference)
//
#include <hip/hip_runtime.h>

#define DIM   256
#define HW_   1024
#define NROWS 32768
#define KEMB  4096

// ---------------- ws layout ----------------
// [0,       131072)  int    idx[32768]
// [131072,  262144)  float  S[32768]   (fallback path only)
// [262144,  278528)  float  E[4096]
// [278528,  278536)  double loss_sum
// [278536,  278540)  int    done
// [278592,  409664)  int    cnt[32768]
// [540736,  1589312) int    cand[32768][8]
// [1589312, 3686464) short  ebuf[1048576]  (bf16, 16x16-frag-major, 2 MB)
#define WS_S_OFF    131072
#define WS_E_OFF    262144
#define WS_LOSS_OFF 278528
#define WS_DONE_OFF 278536
#define WS_CNT_OFF  278592
#define WS_CAND_OFF 540736
#define WS_EBUF_OFF 1589312
#define WS_NEEDED   3686464
#define RESCUE_W    1.5e-4f

typedef __attribute__((ext_vector_type(8))) short bf16x8;
typedef __attribute__((ext_vector_type(4))) float f32x4;

__device__ __forceinline__ unsigned short f2bf(float v) {
  unsigned u = __float_as_uint(v);
  return (unsigned short)((u + 0x7FFFu + ((u >> 16) & 1u)) >> 16);
}

// min over the 16-lane DPP row (lanes quad*16 + 0..15) via ROW_ROR rotations.
// Pure VALU (no ds_swizzle / LDS pipe). All 16 lanes end with the row min.
// [R4/R13 HW-verified primitive, absmax 0.]
__device__ __forceinline__ float rowmin16_dpp(float v) {
  int x = __float_as_int(v), y;
  y = __builtin_amdgcn_update_dpp(0, x, 0x121, 0xF, 0xF, true);  // ROW_ROR:1
  x = __float_as_int(fminf(__int_as_float(x), __int_as_float(y)));
  y = __builtin_amdgcn_update_dpp(0, x, 0x122, 0xF, 0xF, true);  // ROW_ROR:2
  x = __float_as_int(fminf(__int_as_float(x), __int_as_float(y)));
  y = __builtin_amdgcn_update_dpp(0, x, 0x124, 0xF, 0xF, true);  // ROW_ROR:4
  x = __float_as_int(fminf(__int_as_float(x), __int_as_float(y)));
  y = __builtin_amdgcn_update_dpp(0, x, 0x128, 0xF, 0xF, true);  // ROW_ROR:8
  x = __float_as_int(fminf(__int_as_float(x), __int_as_float(y)));
  return __int_as_float(x);
}

// ---------- numpy-pairwise row sums of squares ----------
__device__ __forceinline__ float np_sumsq_128(const float* q, int stride) {
#pragma clang fp contract(off)
  float r[8];
#pragma unroll
  for (int i = 0; i < 8; ++i) { float v = q[i * stride]; r[i] = v * v; }
  for (int blk = 8; blk < 128; blk += 8) {
#pragma unroll
    for (int i = 0; i < 8; ++i) {
      float v = q[(blk + i) * stride];
      float sq = v * v;
      r[i] = r[i] + sq;
    }
  }
  return ((r[0] + r[1]) + (r[2] + r[3])) + ((r[4] + r[5]) + (r[6] + r[7]));
}

// ---------- prep v2: init + E norms (+S only on fallback path) + pack ------
__global__ __launch_bounds__(256) void prep_kernel(
    const float* __restrict__ z, const float* __restrict__ emb,
    float* __restrict__ S, float* __restrict__ E, short* __restrict__ ebuf,
    double* __restrict__ loss_sum, int* __restrict__ done, int do_filter) {
#pragma clang fp contract(off)
  if (blockIdx.x < 144) {
    int t = blockIdx.x * 256 + threadIdx.x;
    if (t == 0) { loss_sum[0] = 0.0; done[0] = 0; }
    if (t < NROWS) {
      if (!do_filter) {
        int b = t >> 10, hw = t & 1023;
        const float* p = z + (size_t)b * (DIM * HW_) + hw;
        float s0 = np_sumsq_128(p, HW_);
        float s1 = np_sumsq_128(p + 128 * HW_, HW_);
        S[t] = s0 + s1;
      }
    } else if (t < NROWS + KEMB) {
      int j = t - NROWS;
      const float* p = emb + (size_t)j * DIM;
      float s0 = np_sumsq_128(p, 1);
      float s1 = np_sumsq_128(p + 128, 1);
      E[j] = s0 + s1;
    }
  } else {
    if (!do_filter) return;
    int u = (blockIdx.x - 144) * 256 + threadIdx.x;   // 0..131071
    int lane = u & 63;
    int ks = (u >> 6) & 7;
    int g16 = u >> 9;
    int j = g16 * 16 + (lane & 15);
    int kb = ks * 32 + (lane >> 4) * 8;
    const float* p = emb + (size_t)j * DIM + kb;
    short out[8];
#pragma unroll
    for (int i = 0; i < 8; ++i) out[i] = (short)f2bf(p[i]);
    *(bf16x8*)(ebuf + (size_t)u * 8) = *(bf16x8*)out;
  }
}

// ---------- filter v6.2 (R13-proven, ~106 us): single sweep ----------
// Single-sweep + provisional emission (R12) + cheap pass A/B (R13):
// acc transformed in-place to g; row-min via rowmin16_dpp (VALU pipe);
// provisional emission vs running thr into 64-deep per-row LDS; fixup
// after exact cross-wave thr combine keeps exactly the two-sweep set.
// Overflow -> cnt_g=KEMB -> exact full-scan fallback. Bit-identical.
// Regs: (512,4) pins total <=128 = 2 blocks/CU (R11/R12 lesson).
// [R4: predicates on top of both sweeps lose. R7: no chains in here.]
#define CCAP 64
__global__ __launch_bounds__(512, 4) void filter2_kernel(
    const float* __restrict__ z, const short* __restrict__ ebuf,
    const float* __restrict__ E, int* __restrict__ cnt_g,
    int* __restrict__ cand_g) {
  __shared__ __align__(16) short Ab[32 * 512];   // 32 KB, fragment-major
  __shared__ float rowmin_l[64][8];
  __shared__ float thr_l[64];
  __shared__ int   cnt_l[64];
  __shared__ int   cand_l[64][CCAP + 1];         // 16.25 KB, padded stride
  __shared__ float gv_l[64][CCAP + 1];           // 16.25 KB

  const int t = threadIdx.x;
  const int w = t >> 6, lane = t & 63;
  const int quad = lane >> 4, l16 = lane & 15;
  const int nb = blockIdx.x * 64;
  const int b = nb >> 10, hwb = nb & 1023;   // 64 | 1024: no b straddle

  // ---- cooperative A stage: wave w converts k-slice ks=w, mt=0..3 ----
  {
    const float* zb2 = z + (size_t)b * (DIM * HW_) + hwb;
    const int k0 = w * 32 + quad * 8;
#pragma unroll
    for (int mt = 0; mt < 4; ++mt) {
      const int r = mt * 16 + l16;
      short tmp[8];
#pragma unroll
      for (int i = 0; i < 8; ++i)
        tmp[i] = (short)f2bf(zb2[(size_t)(k0 + i) * HW_ + r]);
      *(bf16x8*)(Ab + ((mt * 8 + w) * 64 + lane) * 8) = *(bf16x8*)tmp;
    }
  }
  if (t < 64) cnt_l[t] = 0;
  __syncthreads();

  const f32x4 zero = {0.0f, 0.0f, 0.0f, 0.0f};
  const short* Abl = Ab + lane * 8;          // per-thread frag base

  // ================= single sweep: min + provisional emission =============
  float runmin[4][4];
#pragma unroll
  for (int mt = 0; mt < 4; ++mt)
#pragma unroll
    for (int rg = 0; rg < 4; ++rg) runmin[mt][rg] = 3.0e38f;

#pragma unroll 1
  for (int grp = 0; grp < 8; ++grp) {
    const int jb = w * 512 + grp * 64;
    const int g16b = jb >> 4;
    f32x4 acc[4][4];
#pragma unroll
    for (int jt = 0; jt < 4; ++jt)
#pragma unroll
      for (int mt = 0; mt < 4; ++mt) acc[jt][mt] = zero;
#pragma unroll 1
    for (int ks = 0; ks < 8; ++ks) {
      bf16x8 av[4];
#pragma unroll
      for (int mt = 0; mt < 4; ++mt)
        av[mt] = *(const bf16x8*)(Abl + (mt * 8 + ks) * 512);
#pragma unroll
      for (int jt = 0; jt < 4; ++jt) {
        bf16x8 bfr = *(const bf16x8*)(ebuf +
            ((size_t)(g16b + jt) * 8 + ks) * 512 + lane * 8);
#pragma unroll
        for (int mt = 0; mt < 4; ++mt)
          acc[jt][mt] = __builtin_amdgcn_mfma_f32_16x16x32_bf16(
              av[mt], bfr, acc[jt][mt], 0, 0, 0);
      }
    }
    float Ejv[4];
#pragma unroll
    for (int jt = 0; jt < 4; ++jt) Ejv[jt] = E[jb + jt * 16 + l16];

    // in-place transform: acc <- g = E_j - 2*M (single fmaf per cell)
#pragma unroll
    for (int jt = 0; jt < 4; ++jt)
#pragma unroll
      for (int mt = 0; mt < 4; ++mt)
#pragma unroll
        for (int rg = 0; rg < 4; ++rg)
          acc[jt][mt][rg] = fmaf(-2.0f, acc[jt][mt][rg], Ejv[jt]);

    // pass A: running ROW min per (mt,rg) via DPP (VALU pipe, no LDS ops)
#pragma unroll
    for (int mt = 0; mt < 4; ++mt)
#pragma unroll
      for (int rg = 0; rg < 4; ++rg) {
        float gm = fminf(fminf(acc[0][mt][rg], acc[1][mt][rg]),
                         fminf(acc[2][mt][rg], acc[3][mt][rg]));
        gm = rowmin16_dpp(gm);
        runmin[mt][rg] = fminf(runmin[mt][rg], gm);
      }

    // pass B: provisional emission vs running thr (g already in acc)
#pragma unroll
    for (int jt = 0; jt < 4; ++jt) {
      int jcol = jb + jt * 16 + l16;
#pragma unroll
      for (int mt = 0; mt < 4; ++mt)
#pragma unroll
        for (int rg = 0; rg < 4; ++rg) {
          float g = acc[jt][mt][rg];
          if (g <= runmin[mt][rg] + RESCUE_W) {
            int rl = mt * 16 + quad * 4 + rg;
            int slot = atomicAdd(&cnt_l[rl], 1);
            if (slot < CCAP) { cand_l[rl][slot] = jcol; gv_l[rl][slot] = g; }
          }
        }
    }
  }

  // cross-wave thr combine (runmin already row-level & quad-uniform)
  if (l16 == 0) {
#pragma unroll
    for (int mt = 0; mt < 4; ++mt)
#pragma unroll
      for (int rg = 0; rg < 4; ++rg)
        rowmin_l[mt * 16 + quad * 4 + rg][w] = runmin[mt][rg];
  }
  __syncthreads();
  if (t < 64) {
    float m0 = fminf(fminf(rowmin_l[t][0], rowmin_l[t][1]),
                     fminf(rowmin_l[t][2], rowmin_l[t][3]));
    float m1 = fminf(fminf(rowmin_l[t][4], rowmin_l[t][5]),
                     fminf(rowmin_l[t][6], rowmin_l[t][7]));
    thr_l[t] = fminf(m0, m1) + RESCUE_W;
  }
  __syncthreads();

  // ================= fixup: exact survivor filter =================
  if (t < 64) {
    int m = cnt_l[t];
    float thr = thr_l[t];
    if (m > CCAP) {
      cnt_g[nb + t] = KEMB;                  // dropped emissions: full scan
    } else {
      int sc = 0;
      for (int q = 0; q < m; ++q) {
        if (gv_l[t][q] <= thr) {
          if (sc < 8) cand_g[(size_t)(nb + t) * 8 + sc] = cand_l[t][q];
          ++sc;
        }
      }
      cnt_g[nb + t] = sc;                    // == two-sweep count exactly
    }
  }
}

// ---------- rescue v2.1 (R9-proven): R5 staging + 4-parallel chains ----------
#define XPAD 257
__global__ __launch_bounds__(256, 2) void exact_cand_kernel(
    const float* __restrict__ z, const float* __restrict__ emb,
    const float* __restrict__ E,
    const int* __restrict__ cnt_g, const int* __restrict__ cand_g,
    int* __restrict__ idx_out, float* __restrict__ idxf_out) {
#pragma clang fp contract(off)
  __shared__ float z_l[64 * XPAD];
  const int t = threadIdx.x;
  const int nb = blockIdx.x * 64;
  const int b = nb >> 10, hwb = nb & 1023;   // 64 | 1024: no b straddle
  const float* zb = z + (size_t)b * (DIM * HW_) + hwb;
#pragma unroll
  for (int i = 0; i < 16; ++i) {
    int flat = i * 256 + t;
    int d = flat >> 4, r4 = flat & 15;
    float4 v = *(const float4*)(zb + (size_t)d * HW_ + r4 * 4);
    z_l[(r4 * 4 + 0) * XPAD + d] = v.x;
    z_l[(r4 * 4 + 1) * XPAD + d] = v.y;
    z_l[(r4 * 4 + 2) * XPAD + d] = v.z;
    z_l[(r4 * 4 + 3) * XPAD + d] = v.w;
  }
  __syncthreads();

  const int r = t >> 2, p = t & 3;           // 64 rows x 4 chains
  const int row = nb + r;
  const float* zrow = z_l + r * XPAD;        // z[k] at zrow[k], bit-identical
  float s;
  {
    float s0 = np_sumsq_128(zrow, 1);
    float s1 = np_sumsq_128(zrow + 128, 1);
    s = s0 + s1;
  }
  int c = cnt_g[row];
  float bd = 3.0e38f; int bj = 0x7fffffff;
  if (c <= 8) {
    for (int q = p; q < c; q += 4) {
      int j = cand_g[(size_t)row * 8 + q];
      const float* e = emb + (size_t)j * DIM;
      float acc = 0.0f;
#pragma unroll 8
      for (int k4 = 0; k4 < 64; ++k4) {        // sequential k ascending
        float4 ev = *(const float4*)(e + k4 * 4);
        acc = fmaf(zrow[k4 * 4 + 0], ev.x, acc);
        acc = fmaf(zrow[k4 * 4 + 1], ev.y, acc);
        acc = fmaf(zrow[k4 * 4 + 2], ev.z, acc);
        acc = fmaf(zrow[k4 * 4 + 3], ev.w, acc);
      }
      float d = fmaf(-2.0f, acc, s + E[j]);
      if (d < bd || (d == bd && j < bj)) { bd = d; bj = j; }
    }
  } else if (p == 0) {
    for (int j = 0; j < KEMB; ++j) {           // overflow fallback (P~0)
      const float* e = emb + (size_t)j * DIM;
      float acc = 0.0f;
      for (int k4 = 0; k4 < 64; ++k4) {
        float4 ev = *(const float4*)(e + k4 * 4);
        acc = fmaf(zrow[k4 * 4 + 0], ev.x, acc);
        acc = fmaf(zrow[k4 * 4 + 1], ev.y, acc);
        acc = fmaf(zrow[k4 * 4 + 2], ev.z, acc);
        acc = fmaf(zrow[k4 * 4 + 3], ev.w, acc);
      }
      float d = fmaf(-2.0f, acc, s + E[j]);
      if (d < bd || (d == bd && j < bj)) { bd = d; bj = j; }
    }
  }
#pragma unroll
  for (int m = 1; m <= 2; m <<= 1) {           // lexicographic (d,j) reduce
    float od = __shfl_xor(bd, m, 64);
    int   oj = __shfl_xor(bj, m, 64);
    if (od < bd || (od == bd && oj < bj)) { bd = od; bj = oj; }
  }
  if (p == 0) { idx_out[row] = bj; idxf_out[row] = (float)bj; }
}

// ---------- fallback fp32 kernel (R2 version, known-passing) ----------
#define RT 64
#define JT 256
#define KC 16
__global__ __launch_bounds__(256, 2) void dist_argmin_kernel(
    const float* __restrict__ z, const float* __restrict__ emb,
    const float* __restrict__ S, const float* __restrict__ E,
    int* __restrict__ idx_out, float* __restrict__ idxf_out) {
  __shared__ float zt[DIM * RT];
  __shared__ float et[KC * JT];
  const int t  = threadIdx.x;
  const int g  = t & 31;
  const int tr = t >> 5;
  const int nb = blockIdx.x * RT;
  const int b  = nb >> 10;
  const int hwb = nb & 1023;
  const float* zb = z + (size_t)b * (DIM * HW_) + hwb;
#pragma unroll
  for (int i = 0; i < 16; ++i) {
    int flat = t + i * 256;
    int k  = flat >> 4;
    int r4 = flat & 15;
    float4 v = *(const float4*)(zb + (size_t)k * HW_ + r4 * 4);
    *(float4*)(zt + flat * 4) = v;
  }
  float bestd[8];
  int   bestj[8];
#pragma unroll
  for (int i = 0; i < 8; ++i) { bestd[i] = 3.0e38f; bestj[i] = 0; }
  float Sreg[8];
#pragma unroll
  for (int rr = 0; rr < 8; ++rr) Sreg[rr] = S[nb + tr * 8 + rr];
  float4 pf[4];
#pragma unroll
  for (int q = 0; q < 4; ++q) {
    int cid = q * 256 + t;
    pf[q] = *(const float4*)(emb + (size_t)(cid >> 2) * DIM + (cid & 3) * 4);
  }
  for (int jt = 0; jt < KEMB / JT; ++jt) {
    float acc[8][8];
#pragma unroll
    for (int rr = 0; rr < 8; ++rr)
#pragma unroll
      for (int c = 0; c < 8; ++c) acc[rr][c] = 0.0f;
    for (int kc = 0; kc < DIM / KC; ++kc) {
      __syncthreads();
#pragma unroll
      for (int q = 0; q < 4; ++q) {
        int cid = q * 256 + t;
        int j = cid >> 2, k4 = cid & 3;
        et[(k4 * 4 + 0) * JT + j] = pf[q].x;
        et[(k4 * 4 + 1) * JT + j] = pf[q].y;
        et[(k4 * 4 + 2) * JT + j] = pf[q].z;
        et[(k4 * 4 + 3) * JT + j] = pf[q].w;
      }
      int s = jt * (DIM / KC) + kc + 1;
      if (s < (KEMB / JT) * (DIM / KC)) {
        int njt = s >> 4, nkc = s & 15;
        const float* base = emb + (size_t)njt * JT * DIM + nkc * KC;
#pragma unroll
        for (int q = 0; q < 4; ++q) {
          int cid = q * 256 + t;
          pf[q] = *(const float4*)(base + (size_t)(cid >> 2) * DIM + (cid & 3) * 4);
        }
      }
      __syncthreads();
      const float* ztk = zt + (kc * KC) * RT;
#pragma unroll
      for (int kk = 0; kk < KC; ++kk) {
        float4 z0 = *(const float4*)(ztk + kk * RT + tr * 8);
        float4 z1 = *(const float4*)(ztk + kk * RT + tr * 8 + 4);
        float2 e0 = *(const float2*)(et + kk * JT + g * 2);
        float2 e1 = *(const float2*)(et + kk * JT + 64 + g * 2);
        float2 e2 = *(const float2*)(et + kk * JT + 128 + g * 2);
        float2 e3 = *(const float2*)(et + kk * JT + 192 + g * 2);
        float zr[8] = {z0.x, z0.y, z0.z, z0.w, z1.x, z1.y, z1.z, z1.w};
        float ev[8] = {e0.x, e0.y, e1.x, e1.y, e2.x, e2.y, e3.x, e3.y};
#pragma unroll
        for (int rr = 0; rr < 8; ++rr)
#pragma unroll
          for (int c = 0; c < 8; ++c)
            acc[rr][c] = fmaf(zr[rr], ev[c], acc[rr][c]);
      }
    }
    int jb = jt * JT;
    float Ereg[8];
#pragma unroll
    for (int c = 0; c < 8; ++c)
      Ereg[c] = E[jb + (c >> 1) * 64 + g * 2 + (c & 1)];
#pragma unroll
    for (int rr = 0; rr < 8; ++rr)
#pragma unroll
      for (int c = 0; c < 8; ++c) {
        float A = Sreg[rr] + Ereg[c];
        float d = fmaf(-2.0f, acc[rr][c], A);
        int j = jb + (c >> 1) * 64 + g * 2 + (c & 1);
        if (d < bestd[rr] || (d == bestd[rr] && j < bestj[rr])) {
          bestd[rr] = d; bestj[rr] = j;
        }
      }
  }
  __syncthreads();
  float* rd = et;
  int*   rj = (int*)(et + 2048);
#pragma unroll
  for (int rr = 0; rr < 8; ++rr) {
    rd[(tr * 8 + rr) * 32 + g] = bestd[rr];
    rj[(tr * 8 + rr) * 32 + g] = bestj[rr];
  }
  __syncthreads();
  if (t < RT) {
    float bd = rd[t * 32];
    int   bj = rj[t * 32];
    for (int c = 1; c < 32; ++c) {
      float d2 = rd[t * 32 + c];
      int   j2 = rj[t * 32 + c];
      if (d2 < bd || (d2 == bd && j2 < bj)) { bd = d2; bj = j2; }
    }
    idx_out[nb + t]  = bj;
    idxf_out[nb + t] = (float)bj;
  }
}

// ---------- epilogue v4 (R14): d-split, 64 rows x 128 d per block ----------
// R13's epilogue was capped at 2 blocks/CU by its 65.8 KB eq tile (8
// waves/CU for a latency-bound kernel with 64 serial dc iterations).
// Split along d (NOT rows - R8's row-split shrank the hw-coalescing
// segments): grid 1024, block = 64 rows x 128-d half. eq = 64 x 129
// floats = 33.0 KB -> 4 blocks/CU (2x waves), 32 dc iterations (half
// the serial chain). EPAD2=129 == 1 mod 32 -> STE-phase LDS reads stay
// conflict-free (2 lanes/bank). Gather: 8 float4 loads/thread (512B
// contiguous per row), scalar LDS stores (keeps the odd stride). Both
// d-half blocks read the same 64 idx (L2-hot). Same STE math per elem;
// loss = same summands, different atomicAdd grouping (R6-verified
// tolerated); done terminal count 1023.
#define EPAD2 129
__global__ __launch_bounds__(256) void epilogue_kernel(
    const float* __restrict__ z, const float* __restrict__ emb,
    const int* __restrict__ idx, float* __restrict__ out0,
    double* __restrict__ loss_sum, int* __restrict__ done,
    float* __restrict__ out_loss) {
#pragma clang fp contract(off)
  __shared__ float eq[64 * EPAD2];
  __shared__ int   iv_l[64];
  __shared__ double wsum[4];
  const int t = threadIdx.x, w = t >> 6, lane = t & 63;
  const int nb = (blockIdx.x >> 1) * 64;
  const int dh = (blockIdx.x & 1) * 128;         // d-half base
  const int b = nb >> 10, hwb = nb & 1023;

  if (t < 64) iv_l[t] = idx[nb + t];
  __syncthreads();
  const float4* emb4 = (const float4*)emb;
  const int dh4 = dh >> 2;                       // 0 or 32
#pragma unroll
  for (int i = 0; i < 8; ++i) {
    int flat = i * 256 + t;
    int r = flat >> 5, c4 = flat & 31;
    float4 v = emb4[(size_t)iv_l[r] * 64 + dh4 + c4];
    float* dst = eq + r * EPAD2 + c4 * 4;
    dst[0] = v.x; dst[1] = v.y; dst[2] = v.z; dst[3] = v.w;
  }
  __syncthreads();

  double acc = 0.0;
  const float* zb = z + (size_t)b * (DIM * HW_) + hwb;
  float* ob = out0 + (size_t)b * (DIM * HW_) + hwb;
  for (int dc = 0; dc < 32; ++dc) {
    int dl = dc * 4 + w;                         // 0..127 local d
    int d  = dh + dl;
    float zp = zb[(size_t)d * HW_ + lane];
    float zq = eq[lane * EPAD2 + dl];
    float td = zq - zp;                   // fl(z_q - zp)
    ob[(size_t)d * HW_ + lane] = zp + td; // fl(zp + fl(z_q - zp))
    acc += (double)(td * td);
  }
#pragma unroll
  for (int off = 32; off > 0; off >>= 1) acc += __shfl_down(acc, off, 64);
  if (lane == 0) wsum[w] = acc;
  __syncthreads();
  if (t == 0) {
    double bsum = (wsum[0] + wsum[1]) + (wsum[2] + wsum[3]);
    atomicAdd(loss_sum, bsum);
    __threadfence();
    int prev = atomicAdd(done, 1);
    if (prev == 1023) {
      double m = loss_sum[0] / 8388608.0;
      float mf = (float)m;
      float bb = 10.0f * mf;
      out_loss[0] = mf + bb;
    }
  }
}

extern "C" void kernel_launch(void* const* d_in, const int* in_sizes, int n_in,
                              void* d_out, int out_size, void* d_ws, size_t ws_size,
                              hipStream_t stream) {
  const float* z   = (const float*)d_in[0];
  const float* emb = (const float*)d_in[1];
  float* out = (float*)d_out;
  char* ws = (char*)d_ws;
  int*      idx  = (int*)ws;
  float*    S    = (float*)(ws + WS_S_OFF);
  float*    E    = (float*)(ws + WS_E_OFF);
  double*   ls   = (double*)(ws + WS_LOSS_OFF);
  int*      done = (int*)(ws + WS_DONE_OFF);
  int*      cnt  = (int*)(ws + WS_CNT_OFF);
  int*      cand = (int*)(ws + WS_CAND_OFF);
  short*    ebuf = (short*)(ws + WS_EBUF_OFF);

  const int do_filter = (ws_size >= (size_t)WS_NEEDED) ? 1 : 0;

  prep_kernel<<<656, 256, 0, stream>>>(z, emb, S, E, ebuf, ls, done, do_filter);

  if (do_filter) {
    filter2_kernel<<<512, 512, 0, stream>>>(z, ebuf, E, cnt, cand);
    exact_cand_kernel<<<512, 256, 0, stream>>>(z, emb, E, cnt, cand, idx,
                                               out + 8388609);
  } else {
    dist_argmin_kernel<<<NROWS / RT, 256, 0, stream>>>(z, emb, S, E, idx,
                                                       out + 8388609);
  }

  epilogue_kernel<<<1024, 256, 0, stream>>>(z, emb, idx, out, ls, done,
                                            out + 8388608);
}

// Round 15
// 212.673 us; speedup vs baseline: 1.0983x; 1.0983x over previous
//
#include <hip/hip_runtime.h>

#define DIM   256
#define HW_   1024
#define NROWS 32768
#define KEMB  4096

// ---------------- ws layout ----------------
// [0,       131072)  int    idx[32768]
// [131072,  262144)  float  S[32768]   (fallback path only)
// [262144,  278528)  float  E[4096]
// [278528,  278536)  double loss_sum
// [278536,  278540)  int    done
// [278592,  409664)  int    cnt[32768]
// [540736,  1589312) int    cand[32768][8]
// [1589312, 3686464) short  ebuf[1048576]  (bf16, 16x16-frag-major, 2 MB)
#define WS_S_OFF    131072
#define WS_E_OFF    262144
#define WS_LOSS_OFF 278528
#define WS_DONE_OFF 278536
#define WS_CNT_OFF  278592
#define WS_CAND_OFF 540736
#define WS_EBUF_OFF 1589312
#define WS_NEEDED   3686464
#define RESCUE_W    1.5e-4f

typedef __attribute__((ext_vector_type(8))) short bf16x8;
typedef __attribute__((ext_vector_type(4))) float f32x4;

__device__ __forceinline__ unsigned short f2bf(float v) {
  unsigned u = __float_as_uint(v);
  return (unsigned short)((u + 0x7FFFu + ((u >> 16) & 1u)) >> 16);
}

// min over the 16-lane DPP row (lanes quad*16 + 0..15) via ROW_ROR rotations.
// Pure VALU (no ds_swizzle / LDS pipe). All 16 lanes end with the row min.
// [R4/R13 HW-verified primitive, absmax 0.]
__device__ __forceinline__ float rowmin16_dpp(float v) {
  int x = __float_as_int(v), y;
  y = __builtin_amdgcn_update_dpp(0, x, 0x121, 0xF, 0xF, true);  // ROW_ROR:1
  x = __float_as_int(fminf(__int_as_float(x), __int_as_float(y)));
  y = __builtin_amdgcn_update_dpp(0, x, 0x122, 0xF, 0xF, true);  // ROW_ROR:2
  x = __float_as_int(fminf(__int_as_float(x), __int_as_float(y)));
  y = __builtin_amdgcn_update_dpp(0, x, 0x124, 0xF, 0xF, true);  // ROW_ROR:4
  x = __float_as_int(fminf(__int_as_float(x), __int_as_float(y)));
  y = __builtin_amdgcn_update_dpp(0, x, 0x128, 0xF, 0xF, true);  // ROW_ROR:8
  x = __float_as_int(fminf(__int_as_float(x), __int_as_float(y)));
  return __int_as_float(x);
}

// ---------- numpy-pairwise row sums of squares ----------
__device__ __forceinline__ float np_sumsq_128(const float* q, int stride) {
#pragma clang fp contract(off)
  float r[8];
#pragma unroll
  for (int i = 0; i < 8; ++i) { float v = q[i * stride]; r[i] = v * v; }
  for (int blk = 8; blk < 128; blk += 8) {
#pragma unroll
    for (int i = 0; i < 8; ++i) {
      float v = q[(blk + i) * stride];
      float sq = v * v;
      r[i] = r[i] + sq;
    }
  }
  return ((r[0] + r[1]) + (r[2] + r[3])) + ((r[4] + r[5]) + (r[6] + r[7]));
}

// ---------- prep v2: init + E norms (+S only on fallback path) + pack ------
__global__ __launch_bounds__(256) void prep_kernel(
    const float* __restrict__ z, const float* __restrict__ emb,
    float* __restrict__ S, float* __restrict__ E, short* __restrict__ ebuf,
    double* __restrict__ loss_sum, int* __restrict__ done, int do_filter) {
#pragma clang fp contract(off)
  if (blockIdx.x < 144) {
    int t = blockIdx.x * 256 + threadIdx.x;
    if (t == 0) { loss_sum[0] = 0.0; done[0] = 0; }
    if (t < NROWS) {
      if (!do_filter) {
        int b = t >> 10, hw = t & 1023;
        const float* p = z + (size_t)b * (DIM * HW_) + hw;
        float s0 = np_sumsq_128(p, HW_);
        float s1 = np_sumsq_128(p + 128 * HW_, HW_);
        S[t] = s0 + s1;
      }
    } else if (t < NROWS + KEMB) {
      int j = t - NROWS;
      const float* p = emb + (size_t)j * DIM;
      float s0 = np_sumsq_128(p, 1);
      float s1 = np_sumsq_128(p + 128, 1);
      E[j] = s0 + s1;
    }
  } else {
    if (!do_filter) return;
    int u = (blockIdx.x - 144) * 256 + threadIdx.x;   // 0..131071
    int lane = u & 63;
    int ks = (u >> 6) & 7;
    int g16 = u >> 9;
    int j = g16 * 16 + (lane & 15);
    int kb = ks * 32 + (lane >> 4) * 8;
    const float* p = emb + (size_t)j * DIM + kb;
    short out[8];
#pragma unroll
    for (int i = 0; i < 8; ++i) out[i] = (short)f2bf(p[i]);
    *(bf16x8*)(ebuf + (size_t)u * 8) = *(bf16x8*)out;
  }
}

// ---------- filter v6.2 (R13-proven, ~106 us): single sweep ----------
// Single-sweep + provisional emission (R12) + cheap pass A/B (R13):
// acc transformed in-place to g; row-min via rowmin16_dpp (VALU pipe);
// provisional emission vs running thr into 64-deep per-row LDS; fixup
// after exact cross-wave thr combine keeps exactly the two-sweep set.
// Overflow -> cnt_g=KEMB -> exact full-scan fallback. Bit-identical.
// Regs: (512,4) pins total <=128 = 2 blocks/CU (R11/R12 lesson).
// [R4: predicates on top of both sweeps lose. R7: no chains in here.
//  R14: do NOT split the tail kernels into more/smaller blocks.]
#define CCAP 64
__global__ __launch_bounds__(512, 4) void filter2_kernel(
    const float* __restrict__ z, const short* __restrict__ ebuf,
    const float* __restrict__ E, int* __restrict__ cnt_g,
    int* __restrict__ cand_g) {
  __shared__ __align__(16) short Ab[32 * 512];   // 32 KB, fragment-major
  __shared__ float rowmin_l[64][8];
  __shared__ float thr_l[64];
  __shared__ int   cnt_l[64];
  __shared__ int   cand_l[64][CCAP + 1];         // 16.25 KB, padded stride
  __shared__ float gv_l[64][CCAP + 1];           // 16.25 KB

  const int t = threadIdx.x;
  const int w = t >> 6, lane = t & 63;
  const int quad = lane >> 4, l16 = lane & 15;
  const int nb = blockIdx.x * 64;
  const int b = nb >> 10, hwb = nb & 1023;   // 64 | 1024: no b straddle

  // ---- cooperative A stage: wave w converts k-slice ks=w, mt=0..3 ----
  {
    const float* zb2 = z + (size_t)b * (DIM * HW_) + hwb;
    const int k0 = w * 32 + quad * 8;
#pragma unroll
    for (int mt = 0; mt < 4; ++mt) {
      const int r = mt * 16 + l16;
      short tmp[8];
#pragma unroll
      for (int i = 0; i < 8; ++i)
        tmp[i] = (short)f2bf(zb2[(size_t)(k0 + i) * HW_ + r]);
      *(bf16x8*)(Ab + ((mt * 8 + w) * 64 + lane) * 8) = *(bf16x8*)tmp;
    }
  }
  if (t < 64) cnt_l[t] = 0;
  __syncthreads();

  const f32x4 zero = {0.0f, 0.0f, 0.0f, 0.0f};
  const short* Abl = Ab + lane * 8;          // per-thread frag base

  // ================= single sweep: min + provisional emission =============
  float runmin[4][4];
#pragma unroll
  for (int mt = 0; mt < 4; ++mt)
#pragma unroll
    for (int rg = 0; rg < 4; ++rg) runmin[mt][rg] = 3.0e38f;

#pragma unroll 1
  for (int grp = 0; grp < 8; ++grp) {
    const int jb = w * 512 + grp * 64;
    const int g16b = jb >> 4;
    f32x4 acc[4][4];
#pragma unroll
    for (int jt = 0; jt < 4; ++jt)
#pragma unroll
      for (int mt = 0; mt < 4; ++mt) acc[jt][mt] = zero;
#pragma unroll 1
    for (int ks = 0; ks < 8; ++ks) {
      bf16x8 av[4];
#pragma unroll
      for (int mt = 0; mt < 4; ++mt)
        av[mt] = *(const bf16x8*)(Abl + (mt * 8 + ks) * 512);
#pragma unroll
      for (int jt = 0; jt < 4; ++jt) {
        bf16x8 bfr = *(const bf16x8*)(ebuf +
            ((size_t)(g16b + jt) * 8 + ks) * 512 + lane * 8);
#pragma unroll
        for (int mt = 0; mt < 4; ++mt)
          acc[jt][mt] = __builtin_amdgcn_mfma_f32_16x16x32_bf16(
              av[mt], bfr, acc[jt][mt], 0, 0, 0);
      }
    }
    float Ejv[4];
#pragma unroll
    for (int jt = 0; jt < 4; ++jt) Ejv[jt] = E[jb + jt * 16 + l16];

    // in-place transform: acc <- g = E_j - 2*M (single fmaf per cell)
#pragma unroll
    for (int jt = 0; jt < 4; ++jt)
#pragma unroll
      for (int mt = 0; mt < 4; ++mt)
#pragma unroll
        for (int rg = 0; rg < 4; ++rg)
          acc[jt][mt][rg] = fmaf(-2.0f, acc[jt][mt][rg], Ejv[jt]);

    // pass A: running ROW min per (mt,rg) via DPP (VALU pipe, no LDS ops)
#pragma unroll
    for (int mt = 0; mt < 4; ++mt)
#pragma unroll
      for (int rg = 0; rg < 4; ++rg) {
        float gm = fminf(fminf(acc[0][mt][rg], acc[1][mt][rg]),
                         fminf(acc[2][mt][rg], acc[3][mt][rg]));
        gm = rowmin16_dpp(gm);
        runmin[mt][rg] = fminf(runmin[mt][rg], gm);
      }

    // pass B: provisional emission vs running thr (g already in acc)
#pragma unroll
    for (int jt = 0; jt < 4; ++jt) {
      int jcol = jb + jt * 16 + l16;
#pragma unroll
      for (int mt = 0; mt < 4; ++mt)
#pragma unroll
        for (int rg = 0; rg < 4; ++rg) {
          float g = acc[jt][mt][rg];
          if (g <= runmin[mt][rg] + RESCUE_W) {
            int rl = mt * 16 + quad * 4 + rg;
            int slot = atomicAdd(&cnt_l[rl], 1);
            if (slot < CCAP) { cand_l[rl][slot] = jcol; gv_l[rl][slot] = g; }
          }
        }
    }
  }

  // cross-wave thr combine (runmin already row-level & quad-uniform)
  if (l16 == 0) {
#pragma unroll
    for (int mt = 0; mt < 4; ++mt)
#pragma unroll
      for (int rg = 0; rg < 4; ++rg)
        rowmin_l[mt * 16 + quad * 4 + rg][w] = runmin[mt][rg];
  }
  __syncthreads();
  if (t < 64) {
    float m0 = fminf(fminf(rowmin_l[t][0], rowmin_l[t][1]),
                     fminf(rowmin_l[t][2], rowmin_l[t][3]));
    float m1 = fminf(fminf(rowmin_l[t][4], rowmin_l[t][5]),
                     fminf(rowmin_l[t][6], rowmin_l[t][7]));
    thr_l[t] = fminf(m0, m1) + RESCUE_W;
  }
  __syncthreads();

  // ================= fixup: exact survivor filter =================
  if (t < 64) {
    int m = cnt_l[t];
    float thr = thr_l[t];
    if (m > CCAP) {
      cnt_g[nb + t] = KEMB;                  // dropped emissions: full scan
    } else {
      int sc = 0;
      for (int q = 0; q < m; ++q) {
        if (gv_l[t][q] <= thr) {
          if (sc < 8) cand_g[(size_t)(nb + t) * 8 + sc] = cand_l[t][q];
          ++sc;
        }
      }
      cnt_g[nb + t] = sc;                    // == two-sweep count exactly
    }
  }
}

// ---------- rescue v2.1 (R9-proven): R5 staging + 4-parallel chains ----------
#define XPAD 257
__global__ __launch_bounds__(256, 2) void exact_cand_kernel(
    const float* __restrict__ z, const float* __restrict__ emb,
    const float* __restrict__ E,
    const int* __restrict__ cnt_g, const int* __restrict__ cand_g,
    int* __restrict__ idx_out, float* __restrict__ idxf_out) {
#pragma clang fp contract(off)
  __shared__ float z_l[64 * XPAD];
  const int t = threadIdx.x;
  const int nb = blockIdx.x * 64;
  const int b = nb >> 10, hwb = nb & 1023;   // 64 | 1024: no b straddle
  const float* zb = z + (size_t)b * (DIM * HW_) + hwb;
#pragma unroll
  for (int i = 0; i < 16; ++i) {
    int flat = i * 256 + t;
    int d = flat >> 4, r4 = flat & 15;
    float4 v = *(const float4*)(zb + (size_t)d * HW_ + r4 * 4);
    z_l[(r4 * 4 + 0) * XPAD + d] = v.x;
    z_l[(r4 * 4 + 1) * XPAD + d] = v.y;
    z_l[(r4 * 4 + 2) * XPAD + d] = v.z;
    z_l[(r4 * 4 + 3) * XPAD + d] = v.w;
  }
  __syncthreads();

  const int r = t >> 2, p = t & 3;           // 64 rows x 4 chains
  const int row = nb + r;
  const float* zrow = z_l + r * XPAD;        // z[k] at zrow[k], bit-identical
  float s;
  {
    float s0 = np_sumsq_128(zrow, 1);
    float s1 = np_sumsq_128(zrow + 128, 1);
    s = s0 + s1;
  }
  int c = cnt_g[row];
  float bd = 3.0e38f; int bj = 0x7fffffff;
  if (c <= 8) {
    for (int q = p; q < c; q += 4) {
      int j = cand_g[(size_t)row * 8 + q];
      const float* e = emb + (size_t)j * DIM;
      float acc = 0.0f;
#pragma unroll 8
      for (int k4 = 0; k4 < 64; ++k4) {        // sequential k ascending
        float4 ev = *(const float4*)(e + k4 * 4);
        acc = fmaf(zrow[k4 * 4 + 0], ev.x, acc);
        acc = fmaf(zrow[k4 * 4 + 1], ev.y, acc);
        acc = fmaf(zrow[k4 * 4 + 2], ev.z, acc);
        acc = fmaf(zrow[k4 * 4 + 3], ev.w, acc);
      }
      float d = fmaf(-2.0f, acc, s + E[j]);
      if (d < bd || (d == bd && j < bj)) { bd = d; bj = j; }
    }
  } else if (p == 0) {
    for (int j = 0; j < KEMB; ++j) {           // overflow fallback (P~0)
      const float* e = emb + (size_t)j * DIM;
      float acc = 0.0f;
      for (int k4 = 0; k4 < 64; ++k4) {
        float4 ev = *(const float4*)(e + k4 * 4);
        acc = fmaf(zrow[k4 * 4 + 0], ev.x, acc);
        acc = fmaf(zrow[k4 * 4 + 1], ev.y, acc);
        acc = fmaf(zrow[k4 * 4 + 2], ev.z, acc);
        acc = fmaf(zrow[k4 * 4 + 3], ev.w, acc);
      }
      float d = fmaf(-2.0f, acc, s + E[j]);
      if (d < bd || (d == bd && j < bj)) { bd = d; bj = j; }
    }
  }
#pragma unroll
  for (int m = 1; m <= 2; m <<= 1) {           // lexicographic (d,j) reduce
    float od = __shfl_xor(bd, m, 64);
    int   oj = __shfl_xor(bj, m, 64);
    if (od < bd || (od == bd && oj < bj)) { bd = od; bj = oj; }
  }
  if (p == 0) { idx_out[row] = bj; idxf_out[row] = (float)bj; }
}

// ---------- fallback fp32 kernel (R2 version, known-passing) ----------
#define RT 64
#define JT 256
#define KC 16
__global__ __launch_bounds__(256, 2) void dist_argmin_kernel(
    const float* __restrict__ z, const float* __restrict__ emb,
    const float* __restrict__ S, const float* __restrict__ E,
    int* __restrict__ idx_out, float* __restrict__ idxf_out) {
  __shared__ float zt[DIM * RT];
  __shared__ float et[KC * JT];
  const int t  = threadIdx.x;
  const int g  = t & 31;
  const int tr = t >> 5;
  const int nb = blockIdx.x * RT;
  const int b  = nb >> 10;
  const int hwb = nb & 1023;
  const float* zb = z + (size_t)b * (DIM * HW_) + hwb;
#pragma unroll
  for (int i = 0; i < 16; ++i) {
    int flat = t + i * 256;
    int k  = flat >> 4;
    int r4 = flat & 15;
    float4 v = *(const float4*)(zb + (size_t)k * HW_ + r4 * 4);
    *(float4*)(zt + flat * 4) = v;
  }
  float bestd[8];
  int   bestj[8];
#pragma unroll
  for (int i = 0; i < 8; ++i) { bestd[i] = 3.0e38f; bestj[i] = 0; }
  float Sreg[8];
#pragma unroll
  for (int rr = 0; rr < 8; ++rr) Sreg[rr] = S[nb + tr * 8 + rr];
  float4 pf[4];
#pragma unroll
  for (int q = 0; q < 4; ++q) {
    int cid = q * 256 + t;
    pf[q] = *(const float4*)(emb + (size_t)(cid >> 2) * DIM + (cid & 3) * 4);
  }
  for (int jt = 0; jt < KEMB / JT; ++jt) {
    float acc[8][8];
#pragma unroll
    for (int rr = 0; rr < 8; ++rr)
#pragma unroll
      for (int c = 0; c < 8; ++c) acc[rr][c] = 0.0f;
    for (int kc = 0; kc < DIM / KC; ++kc) {
      __syncthreads();
#pragma unroll
      for (int q = 0; q < 4; ++q) {
        int cid = q * 256 + t;
        int j = cid >> 2, k4 = cid & 3;
        et[(k4 * 4 + 0) * JT + j] = pf[q].x;
        et[(k4 * 4 + 1) * JT + j] = pf[q].y;
        et[(k4 * 4 + 2) * JT + j] = pf[q].z;
        et[(k4 * 4 + 3) * JT + j] = pf[q].w;
      }
      int s = jt * (DIM / KC) + kc + 1;
      if (s < (KEMB / JT) * (DIM / KC)) {
        int njt = s >> 4, nkc = s & 15;
        const float* base = emb + (size_t)njt * JT * DIM + nkc * KC;
#pragma unroll
        for (int q = 0; q < 4; ++q) {
          int cid = q * 256 + t;
          pf[q] = *(const float4*)(base + (size_t)(cid >> 2) * DIM + (cid & 3) * 4);
        }
      }
      __syncthreads();
      const float* ztk = zt + (kc * KC) * RT;
#pragma unroll
      for (int kk = 0; kk < KC; ++kk) {
        float4 z0 = *(const float4*)(ztk + kk * RT + tr * 8);
        float4 z1 = *(const float4*)(ztk + kk * RT + tr * 8 + 4);
        float2 e0 = *(const float2*)(et + kk * JT + g * 2);
        float2 e1 = *(const float2*)(et + kk * JT + 64 + g * 2);
        float2 e2 = *(const float2*)(et + kk * JT + 128 + g * 2);
        float2 e3 = *(const float2*)(et + kk * JT + 192 + g * 2);
        float zr[8] = {z0.x, z0.y, z0.z, z0.w, z1.x, z1.y, z1.z, z1.w};
        float ev[8] = {e0.x, e0.y, e1.x, e1.y, e2.x, e2.y, e3.x, e3.y};
#pragma unroll
        for (int rr = 0; rr < 8; ++rr)
#pragma unroll
          for (int c = 0; c < 8; ++c)
            acc[rr][c] = fmaf(zr[rr], ev[c], acc[rr][c]);
      }
    }
    int jb = jt * JT;
    float Ereg[8];
#pragma unroll
    for (int c = 0; c < 8; ++c)
      Ereg[c] = E[jb + (c >> 1) * 64 + g * 2 + (c & 1)];
#pragma unroll
    for (int rr = 0; rr < 8; ++rr)
#pragma unroll
      for (int c = 0; c < 8; ++c) {
        float A = Sreg[rr] + Ereg[c];
        float d = fmaf(-2.0f, acc[rr][c], A);
        int j = jb + (c >> 1) * 64 + g * 2 + (c & 1);
        if (d < bestd[rr] || (d == bestd[rr] && j < bestj[rr])) {
          bestd[rr] = d; bestj[rr] = j;
        }
      }
  }
  __syncthreads();
  float* rd = et;
  int*   rj = (int*)(et + 2048);
#pragma unroll
  for (int rr = 0; rr < 8; ++rr) {
    rd[(tr * 8 + rr) * 32 + g] = bestd[rr];
    rj[(tr * 8 + rr) * 32 + g] = bestj[rr];
  }
  __syncthreads();
  if (t < RT) {
    float bd = rd[t * 32];
    int   bj = rj[t * 32];
    for (int c = 1; c < 32; ++c) {
      float d2 = rd[t * 32 + c];
      int   j2 = rj[t * 32 + c];
      if (d2 < bd || (d2 == bd && j2 < bj)) { bd = d2; bj = j2; }
    }
    idx_out[nb + t]  = bj;
    idxf_out[nb + t] = (float)bj;
  }
}

// ---------- epilogue v2 (R5/R13-proven): LDS-staged gather + STE + loss ----
// [R14 lesson: d-split (1024 blocks) cost +29 us despite 2x occupancy -
// per-block fixed costs dominate this latency-bound tail. Keep 512x64.]
#define EPAD 257
__global__ __launch_bounds__(256) void epilogue_kernel(
    const float* __restrict__ z, const float* __restrict__ emb,
    const int* __restrict__ idx, float* __restrict__ out0,
    double* __restrict__ loss_sum, int* __restrict__ done,
    float* __restrict__ out_loss) {
#pragma clang fp contract(off)
  __shared__ float eq[64 * EPAD];
  __shared__ int   iv_l[64];
  __shared__ double wsum[4];
  const int t = threadIdx.x, w = t >> 6, lane = t & 63;
  const int nb = blockIdx.x * 64;
  const int b = nb >> 10, hwb = nb & 1023;

  if (t < 64) iv_l[t] = idx[nb + t];
  __syncthreads();
  const float4* emb4 = (const float4*)emb;
#pragma unroll
  for (int i = 0; i < 16; ++i) {
    int r = w * 16 + i;
    float4 v = emb4[(size_t)iv_l[r] * 64 + lane];
    *(float4*)(eq + r * EPAD + lane * 4) = v;
  }
  __syncthreads();

  double acc = 0.0;
  const float* zb = z + (size_t)b * (DIM * HW_) + hwb;
  float* ob = out0 + (size_t)b * (DIM * HW_) + hwb;
  for (int dc = 0; dc < 64; ++dc) {
    int d = dc * 4 + w;
    float zp = zb[(size_t)d * HW_ + lane];
    float zq = eq[lane * EPAD + d];
    float td = zq - zp;                   // fl(z_q - zp)
    ob[(size_t)d * HW_ + lane] = zp + td; // fl(zp + fl(z_q - zp))
    acc += (double)(td * td);
  }
#pragma unroll
  for (int off = 32; off > 0; off >>= 1) acc += __shfl_down(acc, off, 64);
  if (lane == 0) wsum[w] = acc;
  __syncthreads();
  if (t == 0) {
    double bsum = (wsum[0] + wsum[1]) + (wsum[2] + wsum[3]);
    atomicAdd(loss_sum, bsum);
    __threadfence();
    int prev = atomicAdd(done, 1);
    if (prev == 511) {
      double m = loss_sum[0] / 8388608.0;
      float mf = (float)m;
      float bb = 10.0f * mf;
      out_loss[0] = mf + bb;
    }
  }
}

extern "C" void kernel_launch(void* const* d_in, const int* in_sizes, int n_in,
                              void* d_out, int out_size, void* d_ws, size_t ws_size,
                              hipStream_t stream) {
  const float* z   = (const float*)d_in[0];
  const float* emb = (const float*)d_in[1];
  float* out = (float*)d_out;
  char* ws = (char*)d_ws;
  int*      idx  = (int*)ws;
  float*    S    = (float*)(ws + WS_S_OFF);
  float*    E    = (float*)(ws + WS_E_OFF);
  double*   ls   = (double*)(ws + WS_LOSS_OFF);
  int*      done = (int*)(ws + WS_DONE_OFF);
  int*      cnt  = (int*)(ws + WS_CNT_OFF);
  int*      cand = (int*)(ws + WS_CAND_OFF);
  short*    ebuf = (short*)(ws + WS_EBUF_OFF);

  const int do_filter = (ws_size >= (size_t)WS_NEEDED) ? 1 : 0;

  prep_kernel<<<656, 256, 0, stream>>>(z, emb, S, E, ebuf, ls, done, do_filter);

  if (do_filter) {
    filter2_kernel<<<512, 512, 0, stream>>>(z, ebuf, E, cnt, cand);
    exact_cand_kernel<<<512, 256, 0, stream>>>(z, emb, E, cnt, cand, idx,
                                               out + 8388609);
  } else {
    dist_argmin_kernel<<<NROWS / RT, 256, 0, stream>>>(z, emb, S, E, idx,
                                                       out + 8388609);
  }

  epilogue_kernel<<<512, 256, 0, stream>>>(z, emb, idx, out, ls, done,
                                           out + 8388608);
}